// Round 10
// baseline (41.221 us; speedup 1.0000x reference)
//
#include <hip/hip_runtime.h>
#include <math.h>

// Problem constants
#define NB 16
#define NC 64
#define NL 4096            // 64*64
#define EPSF 1e-5f
#define LOG_EPSF -11.512925464970229f   // log(1e-5)
#define CC 4               // channels per chunk (= waves per block)
#define NCHUNK 16

// d_ws layout (float offsets)
#define WS_W2T   0         // [64c][64o]  w2[o][c]^2 / r2[o]
#define WS_RHO   4096      // [64]        r2[o] / s22
#define WS_SMAG  4160      // [64][9]     class sums of nws_mag
#define WS_TANG  4736      // [64][9]     class sums of nw_ang
#define WS_IS12  5312      // 1 / sum(w1^2)

typedef float f32x2 __attribute__((ext_vector_type(2)));

// ACC = float4[4] (4 o's), MV = data l-vector, W = 4 o-weights
#define FMA16(ACC, MV, W) \
  (ACC)[0].x = fmaf((MV).x,(W).x,(ACC)[0].x); (ACC)[0].y = fmaf((MV).y,(W).x,(ACC)[0].y); \
  (ACC)[0].z = fmaf((MV).z,(W).x,(ACC)[0].z); (ACC)[0].w = fmaf((MV).w,(W).x,(ACC)[0].w); \
  (ACC)[1].x = fmaf((MV).x,(W).y,(ACC)[1].x); (ACC)[1].y = fmaf((MV).y,(W).y,(ACC)[1].y); \
  (ACC)[1].z = fmaf((MV).z,(W).y,(ACC)[1].z); (ACC)[1].w = fmaf((MV).w,(W).y,(ACC)[1].w); \
  (ACC)[2].x = fmaf((MV).x,(W).z,(ACC)[2].x); (ACC)[2].y = fmaf((MV).y,(W).z,(ACC)[2].y); \
  (ACC)[2].z = fmaf((MV).z,(W).z,(ACC)[2].z); (ACC)[2].w = fmaf((MV).w,(W).z,(ACC)[2].w); \
  (ACC)[3].x = fmaf((MV).x,(W).w,(ACC)[3].x); (ACC)[3].y = fmaf((MV).y,(W).w,(ACC)[3].y); \
  (ACC)[3].z = fmaf((MV).z,(W).w,(ACC)[3].z); (ACC)[3].w = fmaf((MV).w,(W).w,(ACC)[3].w);

// ---------------- prep: all weight math -> d_ws ----------------
__global__ __launch_bounds__(256) void prep_kernel(
    const float* __restrict__ wm, const float* __restrict__ wa,
    const float* __restrict__ w1, const float* __restrict__ w2,
    float* __restrict__ ws)
{
    __shared__ float r2s[64];
    __shared__ float red[3][4];
    const int tid  = threadIdx.x;
    const int lane = tid & 63;
    const int wv   = tid >> 6;

    if (tid < 64) {
        float s = 0.f;
        for (int c = 0; c < 64; ++c) { float v = w2[tid * 64 + c]; s = fmaf(v, v, s); }
        r2s[tid] = s;
    }
    float p0 = 0.f, p1 = 0.f, p2 = 0.f;
    {
        float v;
        v = wm[tid]; p0 += v * v;  v = wm[tid + 256]; p0 += v * v;
        v = wa[tid]; p1 += v * v;  v = wa[tid + 256]; p1 += v * v;
        v = w1[tid]; p2 += v * v;  v = w1[tid + 256]; p2 += v * v;
        if (tid < 64) {
            v = wm[tid + 512]; p0 += v * v;
            v = wa[tid + 512]; p1 += v * v;
            v = w1[tid + 512]; p2 += v * v;
        }
    }
    #pragma unroll
    for (int s = 32; s; s >>= 1) {
        p0 += __shfl_down(p0, s); p1 += __shfl_down(p1, s); p2 += __shfl_down(p2, s);
    }
    if (lane == 0) { red[0][wv] = p0; red[1][wv] = p1; red[2][wv] = p2; }
    __syncthreads();
    const float s_wm2 = red[0][0] + red[0][1] + red[0][2] + red[0][3];
    const float s_wa2 = red[1][0] + red[1][1] + red[1][2] + red[1][3];
    const float s_w12 = red[2][0] + red[2][1] + red[2][2] + red[2][3];

    // this block's w2t slice: channels c0..c0+3
    const int c0 = blockIdx.x * 4;
    {
        int c = c0 + (tid >> 6), o = tid & 63;
        float v = w2[o * 64 + c];
        ws[WS_W2T + c * 64 + o] = v * v / r2s[o];
    }

    if (blockIdx.x == 0) {
        if (tid < 64) {
            float s22 = 0.f;
            #pragma unroll
            for (int o = 0; o < 64; ++o) s22 += r2s[o];
            ws[WS_RHO + tid] = r2s[tid] / s22;

            const int c = tid;
            float nm[9], na[9];
            const float inv_m = 1.f / s_wm2, inv_a = 1.f / s_wa2;
            #pragma unroll
            for (int k = 0; k < 9; ++k) {
                float v = wm[c * 9 + k];
                nm[k] = v * v * inv_m;
                na[k] = wa[c * 9 + k] * inv_a;
            }
            #pragma unroll
            for (int ci_ = 0; ci_ < 3; ++ci_) {
                #pragma unroll
                for (int cj = 0; cj < 3; ++cj) {
                    float sm = 0.f, sa = 0.f;
                    #pragma unroll
                    for (int ki = 0; ki < 3; ++ki) {
                        bool vi = (ci_ == 0) ? (ki < 2) : ((ci_ == 2) ? (ki > 0) : true);
                        if (!vi) continue;
                        #pragma unroll
                        for (int kj = 0; kj < 3; ++kj) {
                            bool vj = (cj == 0) ? (kj < 2) : ((cj == 2) ? (kj > 0) : true);
                            if (!vj) continue;
                            sm += nm[ki * 3 + kj];
                            sa += na[ki * 3 + kj];
                        }
                    }
                    ws[WS_SMAG + c * 9 + ci_ * 3 + cj] = sm;
                    ws[WS_TANG + c * 9 + ci_ * 3 + cj] = sa;
                }
            }
        }
        if (tid == 0) ws[WS_IS12] = 1.f / s_w12;
    }
}

// ---------------- fused main ----------------
__global__ __launch_bounds__(256, 2) void fused_kernel(
    const float* __restrict__ x_mag, const float* __restrict__ x_ang,
    const float* __restrict__ w1, const float* __restrict__ ws,
    float* __restrict__ out)
{
    // LDS ~22 KB
    __shared__ __align__(16) float lf2[CC][4][144];     // packed (logmag, ang) per col; col c -> floats 2c..2c+1; pixel j at col j+4
    __shared__ __align__(16) float m1r[2][CC][2][64];   // conv out (mag), parity dbuf
    __shared__ __align__(16) float a1r[2][CC][2][64];   // conv out (ang)
    __shared__ float smag_s[576], tang_s[576];          // [c*9 + class]

    const int tid  = threadIdx.x;
    const int lane = tid & 63;
    const int wv   = tid >> 6;           // 0..3

    // XCD swizzle: 512 % 8 == 0 -> bijective
    const int bid = (blockIdx.x & 7) * 64 + (blockIdx.x >> 3);
    const int b  = bid >> 5;
    const int i0 = (bid & 31) * 2;       // block owns output rows i0, i0+1

    // ---- stage mapping: wave wv stages channel (ch*CC+wv); lane -> (sr, j4) ----
    const int sr = lane >> 4;            // staged row 0..3 -> image row i0-1+sr
    const int j4 = lane & 15;
    const int ir = i0 - 1 + sr;
    const bool ok = ((unsigned)ir < 64u);
    const int irc = ok ? ir : 0;
    const int ci = (ir == 0) ? 0 : ((ir == 63) ? 2 : 1);
    const int kL = ci * 3 + 0, kC = ci * 3 + 1, kR = ci * 3 + 2;
    const float ni = (ci == 1) ? 3.f : 2.f;
    const float nCt = 3.f * ni;
    const float n0 = (j4 == 0)  ? 2.f * ni : nCt;
    const float n3 = (j4 == 15) ? 2.f * ni : nCt;

    const float* spm = x_mag + ((size_t)(b * NC + wv) * NL + irc * 64 + j4 * 4);
    const float* spa = x_ang + ((size_t)(b * NC + wv) * NL + irc * 64 + j4 * 4);

    // chunk-0 prefetch in flight across init
    float4 pfm = *(const float4*)spm;
    float4 pfa = *(const float4*)spa;

    // ---- matmul mapping: tid = rr(b7) | o8(b6-4) | l16(b3-0); 8o x 4l tile ----
    const int mrr = tid >> 7;
    const int o0  = ((tid >> 4) & 7) * 8;
    const int l0  = (tid & 15) * 4;

    const float* w2t_g = ws + WS_W2T;
    const float inv_s12 = ws[WS_IS12];

    // ---------- init: copy class tables, hoisted sentinels ----------
    {
        // 1152 floats: 256 threads x f4 -> 1024, remainder by first 32 threads
        float4 v0 = ((const float4*)(ws + WS_SMAG))[tid & 127];
        if (tid < 128) *(float4*)&smag_s[tid * 4] = v0;
        else           *(float4*)&tang_s[(tid - 128) * 4] = v0;  // same index (tid&127)
        if (tid < 16)  smag_s[512 + tid * 4 + 0] = ws[WS_SMAG + 512 + tid * 4 + 0],
                       smag_s[512 + tid * 4 + 1] = ws[WS_SMAG + 512 + tid * 4 + 1],
                       smag_s[512 + tid * 4 + 2] = ws[WS_SMAG + 512 + tid * 4 + 2],
                       smag_s[512 + tid * 4 + 3] = ws[WS_SMAG + 512 + tid * 4 + 3];
        else if (tid < 32) {
            int t = tid - 16;
            tang_s[512 + t * 4 + 0] = ws[WS_TANG + 512 + t * 4 + 0];
            tang_s[512 + t * 4 + 1] = ws[WS_TANG + 512 + t * 4 + 1];
            tang_s[512 + t * 4 + 2] = ws[WS_TANG + 512 + t * 4 + 2];
            tang_s[512 + t * 4 + 3] = ws[WS_TANG + 512 + t * 4 + 3];
        }
    }
    // chunk-invariant sentinel/pad writes (wave-local)
    if (j4 == 0)  { lf2[wv][sr][6]   = LOG_EPSF; lf2[wv][sr][7]   = 0.f; }
    if (j4 == 15) { lf2[wv][sr][136] = LOG_EPSF; lf2[wv][sr][137] = 0.f; }
    if (!ok) {
        float4 s4; s4.x = LOG_EPSF; s4.y = 0.f; s4.z = LOG_EPSF; s4.w = 0.f;
        *(float4*)&lf2[wv][sr][8 + 8 * j4]  = s4;
        *(float4*)&lf2[wv][sr][12 + 8 * j4] = s4;
    }
    __syncthreads();

    // ---------- main channel loop ----------
    float4 accm[8], acca[8];             // 8 o's x 4 l's, one row, both sides
    #pragma unroll
    for (int oi = 0; oi < 8; ++oi) {
        accm[oi].x = accm[oi].y = accm[oi].z = accm[oi].w = 0.f;
        acca[oi].x = acca[oi].y = acca[oi].z = acca[oi].w = 0.f;
    }

    auto do_matmul = [&](int chm, int pp) {
        const int c0 = chm * CC;
        #pragma unroll
        for (int cc = 0; cc < CC; ++cc) {
            const float* wg = w2t_g + (size_t)(c0 + cc) * 64 + o0;
            float4 w0_ = *(const float4*)(wg);       // VMEM (L1-resident 16KB table)
            float4 w1_ = *(const float4*)(wg + 4);
            float4 mv  = *(const float4*)&m1r[pp][cc][mrr][l0];
            float4 av  = *(const float4*)&a1r[pp][cc][mrr][l0];
            FMA16((&accm[0]), mv, w0_);
            FMA16((&accm[4]), mv, w1_);
            FMA16((&acca[0]), av, w0_);
            FMA16((&acca[4]), av, w1_);  // ang uses same weights; *rho[o] in epilogue
        }
    };

    #pragma unroll 2
    for (int ch = 0; ch < NCHUNK; ++ch) {
        const int p = ch & 1;
        const int cg = ch * CC + wv;

        // ---- conv weights: wave-uniform loads from global ----
        const int cgu = __builtin_amdgcn_readfirstlane(cg);
        const float* w1row = w1 + cgu * 9;
        float q[9];
        #pragma unroll
        for (int k = 0; k < 9; ++k) q[k] = w1row[k];

        // ---- stage(ch): wave-local, packed (m,a) ----
        if (ok) {
            float sC = smag_s[cg * 9 + kC], tC = tang_s[cg * 9 + kC];
            float s0 = (j4 == 0)  ? smag_s[cg * 9 + kL] : sC;
            float s3 = (j4 == 15) ? smag_s[cg * 9 + kR] : sC;
            float t0 = (j4 == 0)  ? tang_s[cg * 9 + kL] : tC;
            float t3 = (j4 == 15) ? tang_s[cg * 9 + kR] : tC;
            float4 v0, v1;
            v0.x = __logf(fmaf(n0,  pfm.x, s0) + EPSF);
            v0.y = pfa.x * t0;
            v0.z = __logf(fmaf(nCt, pfm.y, sC) + EPSF);
            v0.w = pfa.y * tC;
            v1.x = __logf(fmaf(nCt, pfm.z, sC) + EPSF);
            v1.y = pfa.z * tC;
            v1.z = __logf(fmaf(n3,  pfm.w, s3) + EPSF);
            v1.w = pfa.w * t3;
            *(float4*)&lf2[wv][sr][8 + 8 * j4]  = v0;
            *(float4*)&lf2[wv][sr][12 + 8 * j4] = v1;
        }

        // ---- prefetch next chunk (in flight across matmul + conv) ----
        if (ch + 1 < NCHUNK) {
            pfm = *(const float4*)(spm + (size_t)(ch + 1) * CC * NL);
            pfa = *(const float4*)(spa + (size_t)(ch + 1) * CC * NL);
        }

        // ---- matmul(ch-1): reads parity p^1 ----
        if (ch > 0) do_matmul(ch - 1, p ^ 1);

        // ---- finish conv weights ----
        #pragma unroll
        for (int k = 0; k < 9; ++k) q[k] = q[k] * q[k];
        const float r1c = ((q[0] + q[1]) + (q[2] + q[3])) + ((q[4] + q[5]) + (q[6] + q[7])) + q[8];
        const float inv_r1 = 1.f / r1c;
        f32x2 q2[9];
        #pragma unroll
        for (int k = 0; k < 9; ++k) { q2[k].x = q[k]; q2[k].y = q[k]; }

        // ---- conv(ch): packed b64 reads + pk-fma ----
        {
            f32x2 a0; a0.x = 0.f; a0.y = 0.f;
            f32x2 a1; a1.x = 0.f; a1.y = 0.f;
            #pragma unroll
            for (int r_ = 0; r_ < 4; ++r_) {
                const float* rp = &lf2[wv][r_][0];
                f32x2 v0 = *(const f32x2*)(rp + 2 * lane + 6);
                f32x2 v1 = *(const f32x2*)(rp + 2 * lane + 8);
                f32x2 v2 = *(const f32x2*)(rp + 2 * lane + 10);
                if (r_ < 3) {   // output row i0, ki = r_
                    a0 = __builtin_elementwise_fma(q2[r_ * 3 + 0], v0, a0);
                    a0 = __builtin_elementwise_fma(q2[r_ * 3 + 1], v1, a0);
                    a0 = __builtin_elementwise_fma(q2[r_ * 3 + 2], v2, a0);
                }
                if (r_ > 0) {   // output row i0+1, ki = r_-1
                    const int ki = r_ - 1;
                    a1 = __builtin_elementwise_fma(q2[ki * 3 + 0], v0, a1);
                    a1 = __builtin_elementwise_fma(q2[ki * 3 + 1], v1, a1);
                    a1 = __builtin_elementwise_fma(q2[ki * 3 + 2], v2, a1);
                }
            }
            m1r[p][wv][0][lane] = a0.x * inv_r1;
            a1r[p][wv][0][lane] = a0.y * inv_s12;
            m1r[p][wv][1][lane] = a1.x * inv_r1;
            a1r[p][wv][1][lane] = a1.y * inv_s12;
        }
        __syncthreads();   // ONE barrier per chunk: fences m1r/a1r[p]
    }
    do_matmul(NCHUNK - 1, 1);

    // ---------- epilogue ----------
    {
        const float4 rh0 = *(const float4*)(ws + WS_RHO + o0);
        const float4 rh1 = *(const float4*)(ws + WS_RHO + o0 + 4);
        acca[0].x *= rh0.x; acca[0].y *= rh0.x; acca[0].z *= rh0.x; acca[0].w *= rh0.x;
        acca[1].x *= rh0.y; acca[1].y *= rh0.y; acca[1].z *= rh0.y; acca[1].w *= rh0.y;
        acca[2].x *= rh0.z; acca[2].y *= rh0.z; acca[2].z *= rh0.z; acca[2].w *= rh0.z;
        acca[3].x *= rh0.w; acca[3].y *= rh0.w; acca[3].z *= rh0.w; acca[3].w *= rh0.w;
        acca[4].x *= rh1.x; acca[4].y *= rh1.x; acca[4].z *= rh1.x; acca[4].w *= rh1.x;
        acca[5].x *= rh1.y; acca[5].y *= rh1.y; acca[5].z *= rh1.y; acca[5].w *= rh1.y;
        acca[6].x *= rh1.z; acca[6].y *= rh1.z; acca[6].z *= rh1.z; acca[6].w *= rh1.z;
        acca[7].x *= rh1.w; acca[7].y *= rh1.w; acca[7].z *= rh1.w; acca[7].w *= rh1.w;
    }

    #pragma unroll
    for (int oi = 0; oi < 8; ++oi) {
        float4 am = accm[oi], aa = acca[oi];
        float4 oc, os;
        float ex;
        ex = __expf(am.x); oc.x = ex * __cosf(aa.x); os.x = ex * __sinf(aa.x);
        ex = __expf(am.y); oc.y = ex * __cosf(aa.y); os.y = ex * __sinf(aa.y);
        ex = __expf(am.z); oc.z = ex * __cosf(aa.z); os.z = ex * __sinf(aa.z);
        ex = __expf(am.w); oc.w = ex * __cosf(aa.w); os.w = ex * __sinf(aa.w);
        size_t gi = ((size_t)(b * 2) * NC + o0 + oi) * NL + (size_t)(i0 + mrr) * 64 + l0;
        *(float4*)&out[gi] = oc;
        *(float4*)&out[gi + (size_t)NC * NL] = os;
    }
}

extern "C" void kernel_launch(void* const* d_in, const int* in_sizes, int n_in,
                              void* d_out, int out_size, void* d_ws, size_t ws_size,
                              hipStream_t stream) {
    const float* x_mag = (const float*)d_in[0];
    const float* x_ang = (const float*)d_in[1];
    const float* w_mag = (const float*)d_in[2];
    const float* w_ang = (const float*)d_in[3];
    const float* w1    = (const float*)d_in[4];
    const float* w2    = (const float*)d_in[5];
    float* out = (float*)d_out;
    float* ws  = (float*)d_ws;

    prep_kernel<<<16, 256, 0, stream>>>(w_mag, w_ang, w1, w2, ws);
    fused_kernel<<<NB * 32, 256, 0, stream>>>(x_mag, x_ang, w1, ws, out);
}

// Round 11
// 40.611 us; speedup vs baseline: 1.0150x; 1.0150x over previous
//
#include <hip/hip_runtime.h>
#include <math.h>

// Problem constants
#define NB 16
#define NC 64
#define NL 4096            // 64*64
#define EPSF 1e-5f
#define LOG_EPSF -11.512925464970229f   // log(1e-5)
#define CC 4               // channels per chunk (= waves per block)
#define NCHUNK 16

// d_ws layout (float offsets)
#define WS_W2T   0         // [64c][64o]  w2[o][c]^2 / r2[o]
#define WS_RHO   4096      // [64]        r2[o] / s22
#define WS_CLS   4160      // smag[64][9] then tang[64][9], contiguous 1152
#define WS_WQ2   5312      // [64c][9k][2] = (w1^2/rowsum, w1^2/globalsum) pairs

typedef float f32x2 __attribute__((ext_vector_type(2)));

// ACC = float4[4] (4 o's), MV = data l-vector, W = 4 o-weights
#define FMA16(ACC, MV, W) \
  (ACC)[0].x = fmaf((MV).x,(W).x,(ACC)[0].x); (ACC)[0].y = fmaf((MV).y,(W).x,(ACC)[0].y); \
  (ACC)[0].z = fmaf((MV).z,(W).x,(ACC)[0].z); (ACC)[0].w = fmaf((MV).w,(W).x,(ACC)[0].w); \
  (ACC)[1].x = fmaf((MV).x,(W).y,(ACC)[1].x); (ACC)[1].y = fmaf((MV).y,(W).y,(ACC)[1].y); \
  (ACC)[1].z = fmaf((MV).z,(W).y,(ACC)[1].z); (ACC)[1].w = fmaf((MV).w,(W).y,(ACC)[1].w); \
  (ACC)[2].x = fmaf((MV).x,(W).z,(ACC)[2].x); (ACC)[2].y = fmaf((MV).y,(W).z,(ACC)[2].y); \
  (ACC)[2].z = fmaf((MV).z,(W).z,(ACC)[2].z); (ACC)[2].w = fmaf((MV).w,(W).z,(ACC)[2].w); \
  (ACC)[3].x = fmaf((MV).x,(W).w,(ACC)[3].x); (ACC)[3].y = fmaf((MV).y,(W).w,(ACC)[3].y); \
  (ACC)[3].z = fmaf((MV).z,(W).w,(ACC)[3].z); (ACC)[3].w = fmaf((MV).w,(W).w,(ACC)[3].w);

// ---------------- prep: ALL weight math -> d_ws ----------------
__global__ __launch_bounds__(256) void prep_kernel(
    const float* __restrict__ wm, const float* __restrict__ wa,
    const float* __restrict__ w1, const float* __restrict__ w2,
    float* __restrict__ ws)
{
    __shared__ float r2s[64];
    __shared__ float red[3][4];
    const int tid  = threadIdx.x;
    const int lane = tid & 63;
    const int wv   = tid >> 6;

    if (tid < 64) {
        float s = 0.f;
        for (int c = 0; c < 64; ++c) { float v = w2[tid * 64 + c]; s = fmaf(v, v, s); }
        r2s[tid] = s;
    }
    float p0 = 0.f, p1 = 0.f, p2 = 0.f;
    {
        float v;
        v = wm[tid]; p0 += v * v;  v = wm[tid + 256]; p0 += v * v;
        v = wa[tid]; p1 += v * v;  v = wa[tid + 256]; p1 += v * v;
        v = w1[tid]; p2 += v * v;  v = w1[tid + 256]; p2 += v * v;
        if (tid < 64) {
            v = wm[tid + 512]; p0 += v * v;
            v = wa[tid + 512]; p1 += v * v;
            v = w1[tid + 512]; p2 += v * v;
        }
    }
    #pragma unroll
    for (int s = 32; s; s >>= 1) {
        p0 += __shfl_down(p0, s); p1 += __shfl_down(p1, s); p2 += __shfl_down(p2, s);
    }
    if (lane == 0) { red[0][wv] = p0; red[1][wv] = p1; red[2][wv] = p2; }
    __syncthreads();
    const float s_wm2 = red[0][0] + red[0][1] + red[0][2] + red[0][3];
    const float s_wa2 = red[1][0] + red[1][1] + red[1][2] + red[1][3];
    const float s_w12 = red[2][0] + red[2][1] + red[2][2] + red[2][3];

    // this block's w2t slice: channels c0..c0+3
    const int c0 = blockIdx.x * 4;
    {
        int c = c0 + (tid >> 6), o = tid & 63;
        float v = w2[o * 64 + c];
        ws[WS_W2T + c * 64 + o] = v * v / r2s[o];
    }

    if (blockIdx.x == 0) {
        if (tid < 64) {
            float s22 = 0.f;
            #pragma unroll
            for (int o = 0; o < 64; ++o) s22 += r2s[o];
            ws[WS_RHO + tid] = r2s[tid] / s22;

            const int c = tid;
            // class tables
            float nm[9], na[9];
            const float inv_m = 1.f / s_wm2, inv_a = 1.f / s_wa2;
            #pragma unroll
            for (int k = 0; k < 9; ++k) {
                float v = wm[c * 9 + k];
                nm[k] = v * v * inv_m;
                na[k] = wa[c * 9 + k] * inv_a;
            }
            #pragma unroll
            for (int ci_ = 0; ci_ < 3; ++ci_) {
                #pragma unroll
                for (int cj = 0; cj < 3; ++cj) {
                    float sm = 0.f, sa = 0.f;
                    #pragma unroll
                    for (int ki = 0; ki < 3; ++ki) {
                        bool vi = (ci_ == 0) ? (ki < 2) : ((ci_ == 2) ? (ki > 0) : true);
                        if (!vi) continue;
                        #pragma unroll
                        for (int kj = 0; kj < 3; ++kj) {
                            bool vj = (cj == 0) ? (kj < 2) : ((cj == 2) ? (kj > 0) : true);
                            if (!vj) continue;
                            sm += nm[ki * 3 + kj];
                            sa += na[ki * 3 + kj];
                        }
                    }
                    ws[WS_CLS + c * 9 + ci_ * 3 + cj] = sm;
                    ws[WS_CLS + 576 + c * 9 + ci_ * 3 + cj] = sa;
                }
            }
            // pre-normalized packed conv weights
            float q[9]; float r1c = 0.f;
            #pragma unroll
            for (int k = 0; k < 9; ++k) { float v = w1[c * 9 + k]; q[k] = v * v; r1c += q[k]; }
            const float inv_r = 1.f / r1c, inv_s = 1.f / s_w12;
            #pragma unroll
            for (int k = 0; k < 9; ++k) {
                ws[WS_WQ2 + c * 18 + 2 * k]     = q[k] * inv_r;
                ws[WS_WQ2 + c * 18 + 2 * k + 1] = q[k] * inv_s;
            }
        }
    }
}

// ---------------- fused main: 1 output row per block ----------------
__global__ __launch_bounds__(256, 4) void fused_kernel(
    const float* __restrict__ x_mag, const float* __restrict__ x_ang,
    const float* __restrict__ ws, float* __restrict__ out)
{
    // LDS ~15.6 KB -> 4 blocks/CU (grid 1024), 4 independent barrier domains/CU
    __shared__ __align__(16) float lf2[CC][3][144];     // packed (logmag, ang): pixel j at floats 8+2j
    __shared__ __align__(16) float m1r[2][CC][64];      // conv out (mag), parity dbuf
    __shared__ __align__(16) float a1r[2][CC][64];      // conv out (ang)
    __shared__ __align__(16) float cls_s[1152];         // smag[0..575], tang[576..1151]

    const int tid  = threadIdx.x;
    const int lane = tid & 63;
    const int wv   = tid >> 6;           // 0..3

    // XCD swizzle: 1024 % 8 == 0 -> bijective; 128 consecutive bids (2 images) per XCD
    const int bid = (blockIdx.x & 7) * 128 + (blockIdx.x >> 3);
    const int b  = bid >> 6;
    const int iy = bid & 63;             // block owns output row iy

    // ---- stage mapping: wave wv stages channel (ch*CC+wv); lane -> (sr, j4) ----
    const int sr = lane >> 4;            // staged row 0..2 -> image row iy-1+sr (sr==3 idle)
    const int j4 = lane & 15;
    const bool act = (sr < 3);
    const int ir = iy - 1 + sr;
    const bool ok = act && ((unsigned)ir < 64u);
    const int irc = ok ? ir : 0;
    const int ci = (ir == 0) ? 0 : ((ir == 63) ? 2 : 1);
    const int kL = ci * 3 + 0, kC = ci * 3 + 1, kR = ci * 3 + 2;
    const float ni = (ci == 1) ? 3.f : 2.f;
    const float nCt = 3.f * ni;
    const float n0 = (j4 == 0)  ? 2.f * ni : nCt;
    const float n3 = (j4 == 15) ? 2.f * ni : nCt;

    const float* spm = x_mag + ((size_t)(b * NC + wv) * NL + irc * 64 + j4 * 4);
    const float* spa = x_ang + ((size_t)(b * NC + wv) * NL + irc * 64 + j4 * 4);

    // chunk-0 prefetch in flight across init
    float4 pfm, pfa;
    if (act) { pfm = *(const float4*)spm; pfa = *(const float4*)spa; }

    // ---- matmul mapping: tid = o16(b7-4) | l16(b3-0); 4o x 4l x 2 sides ----
    const int o0 = (tid >> 4) * 4;
    const int l0 = (tid & 15) * 4;
    const float* w2t_g = ws + WS_W2T;

    // ---------- init: class tables -> LDS; hoisted sentinels ----------
    for (int t = tid; t < 288; t += 256)
        ((float4*)cls_s)[t] = ((const float4*)(ws + WS_CLS))[t];

    if (act) {
        if (j4 == 0)  { lf2[wv][sr][6]   = LOG_EPSF; lf2[wv][sr][7]   = 0.f; }
        if (j4 == 15) { lf2[wv][sr][136] = LOG_EPSF; lf2[wv][sr][137] = 0.f; }
        if (!ok) {
            float4 s4; s4.x = LOG_EPSF; s4.y = 0.f; s4.z = LOG_EPSF; s4.w = 0.f;
            *(float4*)&lf2[wv][sr][8 + 8 * j4]  = s4;
            *(float4*)&lf2[wv][sr][12 + 8 * j4] = s4;
        }
    }
    __syncthreads();

    // ---------- main channel loop ----------
    float4 accm[4], acca[4];             // 4 o's x 4 l's, both sides
    #pragma unroll
    for (int oi = 0; oi < 4; ++oi) {
        accm[oi].x = accm[oi].y = accm[oi].z = accm[oi].w = 0.f;
        acca[oi].x = acca[oi].y = acca[oi].z = acca[oi].w = 0.f;
    }

    auto do_matmul = [&](int chm, int pp) {
        const int c0 = chm * CC;
        #pragma unroll
        for (int cc = 0; cc < CC; ++cc) {
            const float* wg = w2t_g + (size_t)(c0 + cc) * 64 + o0;
            float4 w_ = *(const float4*)wg;          // VMEM (L1-resident 16KB table)
            float4 mv = *(const float4*)&m1r[pp][cc][l0];
            float4 av = *(const float4*)&a1r[pp][cc][l0];
            FMA16(accm, mv, w_);
            FMA16(acca, av, w_);         // ang uses same weights; *rho[o] in epilogue
        }
    };

    #pragma unroll 2
    for (int ch = 0; ch < NCHUNK; ++ch) {
        const int p = ch & 1;
        const int cg = ch * CC + wv;

        // ---- conv weights: wave-uniform s_loads (pre-normalized pairs) ----
        const int cgu = __builtin_amdgcn_readfirstlane(cg);
        const f32x2* qp = (const f32x2*)(ws + WS_WQ2 + cgu * 18);
        f32x2 q2[9];
        #pragma unroll
        for (int k = 0; k < 9; ++k) q2[k] = qp[k];

        // ---- matmul(ch-1) FIRST: its LDS data is ready after the barrier;
        //      runs while this chunk's prefetch (issued last iter) lands ----
        if (ch > 0) do_matmul(ch - 1, p ^ 1);

        // ---- stage(ch): wave-local, packed (m,a) ----
        if (ok) {
            float sC = cls_s[cg * 9 + kC],       tC = cls_s[576 + cg * 9 + kC];
            float s0 = (j4 == 0)  ? cls_s[cg * 9 + kL] : sC;
            float s3 = (j4 == 15) ? cls_s[cg * 9 + kR] : sC;
            float t0 = (j4 == 0)  ? cls_s[576 + cg * 9 + kL] : tC;
            float t3 = (j4 == 15) ? cls_s[576 + cg * 9 + kR] : tC;
            float4 v0, v1;
            v0.x = __logf(fmaf(n0,  pfm.x, s0) + EPSF);
            v0.y = pfa.x * t0;
            v0.z = __logf(fmaf(nCt, pfm.y, sC) + EPSF);
            v0.w = pfa.y * tC;
            v1.x = __logf(fmaf(nCt, pfm.z, sC) + EPSF);
            v1.y = pfa.z * tC;
            v1.z = __logf(fmaf(n3,  pfm.w, s3) + EPSF);
            v1.w = pfa.w * t3;
            *(float4*)&lf2[wv][sr][8 + 8 * j4]  = v0;
            *(float4*)&lf2[wv][sr][12 + 8 * j4] = v1;
        }

        // ---- prefetch next chunk (covered by conv + barrier + next matmul) ----
        if (act && (ch + 1 < NCHUNK)) {
            pfm = *(const float4*)(spm + (size_t)(ch + 1) * CC * NL);
            pfa = *(const float4*)(spa + (size_t)(ch + 1) * CC * NL);
        }

        // ---- conv(ch): 9 packed b64 reads + 9 pk-fma, pre-normalized weights ----
        {
            f32x2 a0; a0.x = 0.f; a0.y = 0.f;
            #pragma unroll
            for (int r_ = 0; r_ < 3; ++r_) {
                const float* rp = &lf2[wv][r_][0];
                f32x2 v0 = *(const f32x2*)(rp + 2 * lane + 6);
                f32x2 v1 = *(const f32x2*)(rp + 2 * lane + 8);
                f32x2 v2 = *(const f32x2*)(rp + 2 * lane + 10);
                a0 = __builtin_elementwise_fma(q2[r_ * 3 + 0], v0, a0);
                a0 = __builtin_elementwise_fma(q2[r_ * 3 + 1], v1, a0);
                a0 = __builtin_elementwise_fma(q2[r_ * 3 + 2], v2, a0);
            }
            m1r[p][wv][lane] = a0.x;
            a1r[p][wv][lane] = a0.y;
        }
        __syncthreads();   // ONE barrier per chunk: fences m1r/a1r[p]
    }
    do_matmul(NCHUNK - 1, 1);

    // ---------- epilogue ----------
    {
        const float4 rh = *(const float4*)(ws + WS_RHO + o0);
        acca[0].x *= rh.x; acca[0].y *= rh.x; acca[0].z *= rh.x; acca[0].w *= rh.x;
        acca[1].x *= rh.y; acca[1].y *= rh.y; acca[1].z *= rh.y; acca[1].w *= rh.y;
        acca[2].x *= rh.z; acca[2].y *= rh.z; acca[2].z *= rh.z; acca[2].w *= rh.z;
        acca[3].x *= rh.w; acca[3].y *= rh.w; acca[3].z *= rh.w; acca[3].w *= rh.w;
    }

    #pragma unroll
    for (int oi = 0; oi < 4; ++oi) {
        float4 am = accm[oi], aa = acca[oi];
        float4 oc, os;
        float ex;
        ex = __expf(am.x); oc.x = ex * __cosf(aa.x); os.x = ex * __sinf(aa.x);
        ex = __expf(am.y); oc.y = ex * __cosf(aa.y); os.y = ex * __sinf(aa.y);
        ex = __expf(am.z); oc.z = ex * __cosf(aa.z); os.z = ex * __sinf(aa.z);
        ex = __expf(am.w); oc.w = ex * __cosf(aa.w); os.w = ex * __sinf(aa.w);
        size_t gi = ((size_t)(b * 2) * NC + o0 + oi) * NL + (size_t)iy * 64 + l0;
        *(float4*)&out[gi] = oc;
        *(float4*)&out[gi + (size_t)NC * NL] = os;
    }
}

extern "C" void kernel_launch(void* const* d_in, const int* in_sizes, int n_in,
                              void* d_out, int out_size, void* d_ws, size_t ws_size,
                              hipStream_t stream) {
    const float* x_mag = (const float*)d_in[0];
    const float* x_ang = (const float*)d_in[1];
    const float* w_mag = (const float*)d_in[2];
    const float* w_ang = (const float*)d_in[3];
    const float* w1    = (const float*)d_in[4];
    const float* w2    = (const float*)d_in[5];
    float* out = (float*)d_out;
    float* ws  = (float*)d_ws;

    prep_kernel<<<16, 256, 0, stream>>>(w_mag, w_ang, w1, w2, ws);
    fused_kernel<<<NB * 64, 256, 0, stream>>>(x_mag, x_ang, ws, out);
}